// Round 8
// baseline (221.100 us; speedup 1.0000x reference)
//
#include <hip/hip_runtime.h>

#define CT  0.7f
#define CPT 0.5f
#define BB  32
#define TT  2048
#define DD  512
#define MAXR 1025            // T/2 + 1
#define K2_BLOCKS 512
#define K2_WAVES  (K2_BLOCKS * 4)   // 2048 waves
#define WPR (K2_WAVES / BB)         // 64 waves per row

// ws layout (no memset node — ticket zeroed by k_attn, rest written every call):
//   ticket  int             @ 0
//   f_part  float[K2_BLOCKS]@ 256     per-BLOCK feat partial (plain store)
//   vid_row float[BB]       @ 8192    per-row attn-level vid/nruns
//   nq_row  int[BB]         @ 8320    per-row qualified-run count
//   queue   int4[BB*MAXR]   @ 16384   row r's items at queue[r*MAXR + 0..nq_row[r])
//           {base_pos, cnt, maskLo, maskHi}; mask bit i => pos base_pos+i is rep

__global__ __launch_bounds__(256) void k_attn(const float* __restrict__ attn,
                                              int4* __restrict__ queue,
                                              float* __restrict__ vid_row,
                                              int* __restrict__ nq_row,
                                              int* __restrict__ ticket) {
    const int row  = blockIdx.x;
    const int t    = threadIdx.x;
    const int lane = t & 63;
    const int wv   = t >> 6;

    __shared__ float s_cnt[MAXR], s_sum[MAXR], s_mse[MAXR];
    __shared__ int   s_pos[MAXR];
    __shared__ unsigned s_mskL[MAXR], s_mskH[MAXR];
    __shared__ int   s_wsum[4];
    __shared__ float s_part[4];
    __shared__ int   s_nq;

    if (row == 0 && t == 0) *ticket = 0;   // visible to k_feat via kernel boundary

    for (int r = t; r < MAXR; r += 256) {
        s_cnt[r] = 0.f; s_sum[r] = 0.f; s_mse[r] = 0.f;
        s_mskL[r] = 0u; s_mskH[r] = 0u;
    }
    if (t == 0) s_nq = 0;

    const float* arow = attn + row * TT;
    const float4* a4 = (const float4*)arow;
    float4 v0 = a4[t * 2], v1 = a4[t * 2 + 1];
    float a[8] = {v0.x, v0.y, v0.z, v0.w, v1.x, v1.y, v1.z, v1.w};
    float aprev = (t > 0) ? arow[t * 8 - 1] : 0.f;   // prev=false at row start

    bool pred[8], start[8];
    bool pv = aprev > CPT;
    int s = 0;
    #pragma unroll
    for (int j = 0; j < 8; j++) {
        pred[j]  = a[j] > CPT;
        start[j] = pred[j] && !pv;
        pv = pred[j];
        s += start[j] ? 1 : 0;
    }

    // wave inclusive scan (6 shfl steps) + 4-wave combine
    int v = s;
    #pragma unroll
    for (int off = 1; off < 64; off <<= 1) {
        int u = __shfl_up(v, off, 64);
        if (lane >= off) v += u;
    }
    if (lane == 63) s_wsum[wv] = v;
    __syncthreads();   // orders LDS init + s_nq + s_wsum

    int base = 0;
    #pragma unroll
    for (int w = 0; w < 4; w++) base += (w < wv) ? s_wsum[w] : 0;
    const int excl  = base + v - s;
    const int nruns = s_wsum[0] + s_wsum[1] + s_wsum[2] + s_wsum[3];

    int rid[8];
    int run = excl;
    #pragma unroll
    for (int j = 0; j < 8; j++) {
        if (start[j]) run++;
        rid[j] = run - 1;
        if (pred[j]) {
            atomicAdd(&s_cnt[rid[j]], 1.f);
            atomicAdd(&s_sum[rid[j]], a[j]);
            if (start[j]) s_pos[rid[j]] = t * 8 + j;
        }
    }
    __syncthreads();

    for (int r = t; r < nruns; r += 256) s_sum[r] = s_sum[r] / s_cnt[r];
    __syncthreads();

    #pragma unroll
    for (int j = 0; j < 8; j++) {
        if (pred[j]) {
            const int r = rid[j];
            float d = a[j] - s_sum[r];
            atomicAdd(&s_mse[r], d * d);
            if (a[j] > CT) {
                int off = t * 8 + j - s_pos[r];   // run offset; <64 for this input
                if (off < 32) atomicOr(&s_mskL[r], 1u << off);
                else if (off < 64) atomicOr(&s_mskH[r], 1u << (off - 32));
            }
        }
    }
    __syncthreads();

    // append qualified runs into this row's private region (LDS-assigned index,
    // plain global stores — zero contended global RMWs)
    float vid = 0.f;
    for (int r = t; r < nruns; r += 256) {
        const float c = s_cnt[r];
        vid += s_mse[r] / c;
        if ((s_mskL[r] | s_mskH[r]) != 0u) {
            int idx = atomicAdd(&s_nq, 1);   // LDS atomic
            int4 dsc;
            dsc.x = row * TT + s_pos[r];
            dsc.y = (int)c;
            dsc.z = (int)s_mskL[r];
            dsc.w = (int)s_mskH[r];
            queue[row * MAXR + idx] = dsc;
        }
    }

    #pragma unroll
    for (int off = 32; off >= 1; off >>= 1) vid += __shfl_xor(vid, off, 64);
    if (lane == 0) s_part[wv] = vid;
    __syncthreads();   // s_part + s_nq complete
    if (t == 0) {
        float tot = s_part[0] + s_part[1] + s_part[2] + s_part[3];
        vid_row[row] = tot / (float)max(nruns, 1);
        nq_row[row]  = s_nq;
    }
}

__global__ __launch_bounds__(256) void k_feat(const float* __restrict__ feat,
                                              const int4* __restrict__ queue,
                                              const int* __restrict__ nq_row,
                                              const float* __restrict__ vid_row,
                                              int* __restrict__ ticket,
                                              float* __restrict__ f_part,
                                              float* __restrict__ out) {
    __shared__ float s_part[4];
    __shared__ float s_red[3][4];
    __shared__ bool  s_fin;
    const int t     = threadIdx.x;
    const int lane  = t & 63;
    const int wv    = t >> 6;
    const int wid   = blockIdx.x * 4 + wv;
    const int row   = wid & (BB - 1);
    const int wslot = wid >> 5;          // [0, WPR)

    const int n = nq_row[row];
    const int4* qrow = queue + row * MAXR;

    float s = 0.f;
    int i = wslot;
    int4 d = {0, 0, 0, 0};
    if (i < n) d = qrow[i];
    while (i < n) {
        const int inext = i + WPR;
        int4 dnext = d;
        if (inext < n) dnext = qrow[inext];   // prefetch next descriptor
        const unsigned long long mask =
            ((unsigned long long)(unsigned)d.w << 32) | (unsigned)d.z;
        const float inv_cnt = 1.f / (float)d.y;
        const float inv_rep = 1.f / (float)__popcll(mask);
        float4 acc0 = {0, 0, 0, 0}, acc1 = {0, 0, 0, 0};
        for (int k = 0; k < d.y; k++) {
            const float c = inv_cnt - (((mask >> k) & 1ull) ? inv_rep : 0.f);
            const float4* f4 = (const float4*)(feat + (size_t)(d.x + k) * DD);
            float4 x = f4[lane];
            float4 y = f4[lane + 64];
            acc0.x += c * x.x; acc0.y += c * x.y; acc0.z += c * x.z; acc0.w += c * x.w;
            acc1.x += c * y.x; acc1.y += c * y.y; acc1.z += c * y.z; acc1.w += c * y.w;
        }
        s += acc0.x * acc0.x + acc0.y * acc0.y + acc0.z * acc0.z + acc0.w * acc0.w
           + acc1.x * acc1.x + acc1.y * acc1.y + acc1.z * acc1.z + acc1.w * acc1.w;
        d = dnext; i = inext;
    }

    #pragma unroll
    for (int off = 32; off >= 1; off >>= 1) s += __shfl_xor(s, off, 64);
    if (lane == 0) s_part[wv] = s;
    __syncthreads();

    if (t == 0) {
        f_part[blockIdx.x] = s_part[0] + s_part[1] + s_part[2] + s_part[3];
        __threadfence();   // release our plain store before the ticket RMW
        int old = __hip_atomic_fetch_add(ticket, 1, __ATOMIC_ACQ_REL,
                                         __HIP_MEMORY_SCOPE_AGENT);
        s_fin = (old == K2_BLOCKS - 1);
    }
    __syncthreads();

    if (s_fin) {
        // single acquire RMW above synchronizes with every block's release;
        // plain coalesced loads here (per-element acquire loads = R5 disaster)
        float fs = 0.f;
        for (int k = t; k < K2_BLOCKS; k += 256) fs += f_part[k];
        float vs = 0.f, ns = 0.f;
        if (t < BB) { vs = vid_row[t]; ns = (float)nq_row[t]; }
        #pragma unroll
        for (int off = 32; off >= 1; off >>= 1) {
            fs += __shfl_xor(fs, off, 64);
            vs += __shfl_xor(vs, off, 64);
            ns += __shfl_xor(ns, off, 64);
        }
        if (lane == 0) { s_red[0][wv] = fs; s_red[1][wv] = vs; s_red[2][wv] = ns; }
        __syncthreads();
        if (t == 0) {
            float fa = s_red[0][0] + s_red[0][1] + s_red[0][2] + s_red[0][3];
            float va = s_red[1][0] + s_red[1][1] + s_red[1][2] + s_red[1][3];
            float na = s_red[2][0] + s_red[2][1] + s_red[2][2] + s_red[2][3];
            out[0] = fa / (float)DD / fmaxf(na, 1.f) + va / (float)BB;
        }
    }
}

extern "C" void kernel_launch(void* const* d_in, const int* in_sizes, int n_in,
                              void* d_out, int out_size, void* d_ws, size_t ws_size,
                              hipStream_t stream) {
    const float* attn = (const float*)d_in[0];
    const float* feat = (const float*)d_in[1];
    int*   ticket  = (int*)d_ws;
    float* f_part  = (float*)((char*)d_ws + 256);
    float* vid_row = (float*)((char*)d_ws + 8192);
    int*   nq_row  = (int*)((char*)d_ws + 8320);
    int4*  queue   = (int4*)((char*)d_ws + 16384);

    k_attn<<<BB, 256, 0, stream>>>(attn, queue, vid_row, nq_row, ticket);
    k_feat<<<K2_BLOCKS, 256, 0, stream>>>(feat, queue, nq_row, vid_row, ticket,
                                          f_part, (float*)d_out);
}

// Round 9
// 194.495 us; speedup vs baseline: 1.1368x; 1.1368x over previous
//
#include <hip/hip_runtime.h>

#define CT  0.7f
#define CPT 0.5f
#define BB  32
#define TT  2048
#define DD  512
#define MAXR 1025            // T/2 + 1
#define K2_BLOCKS 1024
#define K2_WAVES  (K2_BLOCKS * 4)   // 4096 waves
#define WPR (K2_WAVES / BB)         // 128 waves per row

// ws layout (no zeroing needed — every field written unconditionally each call):
//   f_part  float[K2_WAVES] @ 0       per-wave feat partial (plain store)
//   vid_row float[BB]       @ 16384   per-row attn-level vid/nruns
//   nq_row  int[BB]         @ 16512   per-row qualified-run count
//   queue   int4[BB*MAXR]   @ 32768   row r's items at queue[r*MAXR + 0..nq_row[r])
//           {base_pos, cnt, maskLo, maskHi}; mask bit i => pos base_pos+i is rep

__global__ __launch_bounds__(256) void k_attn(const float* __restrict__ attn,
                                              int4* __restrict__ queue,
                                              float* __restrict__ vid_row,
                                              int* __restrict__ nq_row) {
    const int row  = blockIdx.x;
    const int t    = threadIdx.x;
    const int lane = t & 63;
    const int wv   = t >> 6;

    __shared__ float s_cnt[MAXR], s_sum[MAXR], s_sq[MAXR];
    __shared__ int   s_pos[MAXR];
    __shared__ unsigned s_mskL[MAXR], s_mskH[MAXR];
    __shared__ int   s_wsum[4];
    __shared__ float s_part[4];
    __shared__ int   s_nq;

    for (int r = t; r < MAXR; r += 256) {
        s_cnt[r] = 0.f; s_sum[r] = 0.f; s_sq[r] = 0.f;
        s_mskL[r] = 0u; s_mskH[r] = 0u;
    }
    if (t == 0) s_nq = 0;

    const float* arow = attn + row * TT;
    const float4* a4 = (const float4*)arow;
    float4 v0 = a4[t * 2], v1 = a4[t * 2 + 1];
    float a[8] = {v0.x, v0.y, v0.z, v0.w, v1.x, v1.y, v1.z, v1.w};
    float aprev = (t > 0) ? arow[t * 8 - 1] : 0.f;   // prev=false at row start

    bool pred[8], start[8];
    bool pv = aprev > CPT;
    int s = 0;
    #pragma unroll
    for (int j = 0; j < 8; j++) {
        pred[j]  = a[j] > CPT;
        start[j] = pred[j] && !pv;
        pv = pred[j];
        s += start[j] ? 1 : 0;
    }

    // wave inclusive scan (6 shfl steps) + 4-wave combine
    int v = s;
    #pragma unroll
    for (int off = 1; off < 64; off <<= 1) {
        int u = __shfl_up(v, off, 64);
        if (lane >= off) v += u;
    }
    if (lane == 63) s_wsum[wv] = v;
    __syncthreads();   // orders LDS init + s_nq + s_wsum

    int base = 0;
    #pragma unroll
    for (int w = 0; w < 4; w++) base += (w < wv) ? s_wsum[w] : 0;
    const int excl  = base + v - s;
    const int nruns = s_wsum[0] + s_wsum[1] + s_wsum[2] + s_wsum[3];

    // single accumulation pass: cnt, sum, sum-of-squares, rep mask, start pos
    int run = excl;
    #pragma unroll
    for (int j = 0; j < 8; j++) {
        if (start[j]) run++;
        if (pred[j]) {
            const int r = run - 1;
            atomicAdd(&s_cnt[r], 1.f);
            atomicAdd(&s_sum[r], a[j]);
            atomicAdd(&s_sq[r],  a[j] * a[j]);
            if (start[j]) s_pos[r] = t * 8 + j;
        }
    }
    __syncthreads();
    // mask pass needs s_pos of its run (run start may belong to another thread)
    run = excl;
    #pragma unroll
    for (int j = 0; j < 8; j++) {
        if (start[j]) run++;
        if (pred[j] && a[j] > CT) {
            const int r = run - 1;
            int off = t * 8 + j - s_pos[r];   // run offset; <64 for this input
            if (off < 32) atomicOr(&s_mskL[r], 1u << off);
            else if (off < 64) atomicOr(&s_mskH[r], 1u << (off - 32));
        }
    }
    __syncthreads();

    // per-run wrap-up: variance via E[x^2]-m^2 (one pass), queue append
    float vid = 0.f;
    for (int r = t; r < nruns; r += 256) {
        const float c = s_cnt[r];
        const float m = s_sum[r] / c;
        vid += s_sq[r] / c - m * m;
        if ((s_mskL[r] | s_mskH[r]) != 0u) {
            int idx = atomicAdd(&s_nq, 1);   // LDS atomic
            int4 dsc;
            dsc.x = row * TT + s_pos[r];
            dsc.y = (int)c;
            dsc.z = (int)s_mskL[r];
            dsc.w = (int)s_mskH[r];
            queue[row * MAXR + idx] = dsc;
        }
    }

    #pragma unroll
    for (int off = 32; off >= 1; off >>= 1) vid += __shfl_xor(vid, off, 64);
    if (lane == 0) s_part[wv] = vid;
    __syncthreads();   // s_part + s_nq complete
    if (t == 0) {
        float tot = s_part[0] + s_part[1] + s_part[2] + s_part[3];
        vid_row[row] = tot / (float)max(nruns, 1);
        nq_row[row]  = s_nq;
    }
}

__global__ __launch_bounds__(256) void k_feat(const float* __restrict__ feat,
                                              const int4* __restrict__ queue,
                                              const int* __restrict__ nq_row,
                                              float* __restrict__ f_part) {
    const int lane  = threadIdx.x & 63;
    const int wv    = threadIdx.x >> 6;
    const int wid   = blockIdx.x * 4 + wv;
    const int row   = wid & (BB - 1);
    const int wslot = wid / BB;          // [0, WPR)

    const int n = nq_row[row];
    const int4* qrow = queue + row * MAXR;

    float s = 0.f;
    for (int i = wslot; i < n; i += WPR) {
        const int4 d = qrow[i];
        const unsigned long long mask =
            ((unsigned long long)(unsigned)d.w << 32) | (unsigned)d.z;
        const float inv_cnt = 1.f / (float)d.y;
        const float inv_rep = 1.f / (float)__popcll(mask);
        float4 acc0 = {0, 0, 0, 0}, acc1 = {0, 0, 0, 0};
        for (int k = 0; k < d.y; k++) {
            const float c = inv_cnt - (((mask >> k) & 1ull) ? inv_rep : 0.f);
            const float4* f4 = (const float4*)(feat + (size_t)(d.x + k) * DD);
            float4 x = f4[lane];
            float4 y = f4[lane + 64];
            acc0.x += c * x.x; acc0.y += c * x.y; acc0.z += c * x.z; acc0.w += c * x.w;
            acc1.x += c * y.x; acc1.y += c * y.y; acc1.z += c * y.z; acc1.w += c * y.w;
        }
        s += acc0.x * acc0.x + acc0.y * acc0.y + acc0.z * acc0.z + acc0.w * acc0.w
           + acc1.x * acc1.x + acc1.y * acc1.y + acc1.z * acc1.z + acc1.w * acc1.w;
    }

    #pragma unroll
    for (int off = 32; off >= 1; off >>= 1) s += __shfl_xor(s, off, 64);
    if (lane == 0) f_part[wid] = s;      // plain store, no contention
}

__global__ __launch_bounds__(256) void k_final(const float* __restrict__ f_part,
                                               const float* __restrict__ vid_row,
                                               const int* __restrict__ nq_row,
                                               float* __restrict__ out) {
    __shared__ float s_red[3][4];
    const int t    = threadIdx.x;
    const int lane = t & 63;
    const int wv   = t >> 6;

    float fs = 0.f;
    for (int i = t; i < K2_WAVES; i += 256) fs += f_part[i];
    float vs = 0.f, ns = 0.f;
    if (t < BB) { vs = vid_row[t]; ns = (float)nq_row[t]; }

    #pragma unroll
    for (int off = 32; off >= 1; off >>= 1) {
        fs += __shfl_xor(fs, off, 64);
        vs += __shfl_xor(vs, off, 64);
        ns += __shfl_xor(ns, off, 64);
    }
    if (lane == 0) { s_red[0][wv] = fs; s_red[1][wv] = vs; s_red[2][wv] = ns; }
    __syncthreads();
    if (t == 0) {
        float fa = s_red[0][0] + s_red[0][1] + s_red[0][2] + s_red[0][3];
        float va = s_red[1][0] + s_red[1][1] + s_red[1][2] + s_red[1][3];
        float na = s_red[2][0] + s_red[2][1] + s_red[2][2] + s_red[2][3];
        out[0] = fa / (float)DD / fmaxf(na, 1.f) + va / (float)BB;
    }
}

extern "C" void kernel_launch(void* const* d_in, const int* in_sizes, int n_in,
                              void* d_out, int out_size, void* d_ws, size_t ws_size,
                              hipStream_t stream) {
    const float* attn = (const float*)d_in[0];
    const float* feat = (const float*)d_in[1];
    float* f_part  = (float*)d_ws;
    float* vid_row = (float*)((char*)d_ws + 16384);
    int*   nq_row  = (int*)((char*)d_ws + 16512);
    int4*  queue   = (int4*)((char*)d_ws + 32768);

    k_attn<<<BB, 256, 0, stream>>>(attn, queue, vid_row, nq_row);
    k_feat<<<K2_BLOCKS, 256, 0, stream>>>(feat, queue, nq_row, f_part);
    k_final<<<1, 256, 0, stream>>>(f_part, vid_row, nq_row, (float*)d_out);
}